// Round 6
// baseline (701.656 us; speedup 1.0000x reference)
//
#include <hip/hip_runtime.h>

#define HDIM 64
#define NMODE 5
#define TOUT 6
#define TIN 5
#define NNODE 5
#define FD 10

typedef short bf16x8 __attribute__((ext_vector_type(8)));
typedef float f32x4 __attribute__((ext_vector_type(4)));

#define MFMA16(A,B,C) __builtin_amdgcn_mfma_f32_16x16x32_bf16((A),(B),(C),0,0,0)

// ---------------- ws layout (identical to round 5) ----------------
//   B1E @ 0      len 18432  (NT=12, KT=3)  enc: [Whh | WcET | brz-const]
//   B2E @ 18432  len 2048   enc n-gate x-part
//   B1D @ 20480  len 18432  dec
//   B2D @ 38912  len 2048
//   B3  @ 40960  len 2560   GAT fold
//   BW1 @ 43520  len 4096   out_W1
//   BW2 @ 47616  len 1024   out_W2
//   BC1 @ 48640  len 4096   conf_W1
//   BC2 @ 52736  len 1024   conf_W2
// f32 scratch at float-index 26880.
// Fragment order: ((nt*KT+kt)*64 + lane)*8 + j ; k = kt*32+(lane>>4)*8+j,
// n = nt*16+(lane&15). A built with the same map -> permutation cancels.

__device__ __forceinline__ float fastrcp(float x){ return __builtin_amdgcn_rcpf(x); }
__device__ __forceinline__ float sigm(float x){ return fastrcp(1.f + __expf(-x)); }
__device__ __forceinline__ float tanh_f(float x){ return 2.f*fastrcp(1.f + __expf(-2.f*x)) - 1.f; }

__device__ __forceinline__ short f2b(float f){            // f32 -> bf16 RNE
  unsigned u = __float_as_uint(f);
  unsigned r = (u + 0x7FFFu + ((u >> 16) & 1u)) >> 16;
  return (short)r;
}
__device__ __forceinline__ float b2f(short s){
  return __uint_as_float(((unsigned)(unsigned short)s) << 16);
}
__device__ __forceinline__ int hswz(int row, int col){
  return row*64 + ((((col>>3) ^ (row&7)))<<3) + (col&7);
}

// ---------- setup stage 1: weight folds into f32 scratch (4 blocks) ----------
__global__ void setup_fold(
    const float* __restrict__ embed_W, const float* __restrict__ embed_b,
    const float* __restrict__ enc_Wih, const float* __restrict__ enc_bih,
    const float* __restrict__ dec_Wih, const float* __restrict__ dec_bih,
    const float* __restrict__ proj_W,  const float* __restrict__ proj_b,
    const float* __restrict__ gat_W,   const float* __restrict__ gat_as,
    const float* __restrict__ gat_ad,
    const float* __restrict__ enc_bhh, const float* __restrict__ dec_bhh,
    short* __restrict__ wsb)
{
  float* wsf  = (float*)(wsb) + 26880;
  float* WcET = wsf;        float* WcDT = wsf+1920;
  float* bcE  = wsf+2304;   float* bcD  = wsf+2496;
  float* brzE = wsf+2688;   float* brzD = wsf+2816;
  float* EG   = wsf+2944;   float* ebg0 = wsf+3584;
  float* egs  = wsf+3648;   float* egd  = wsf+3658;
  float* c6   = wsf+3668;
  const int t = threadIdx.x, bx = blockIdx.x;

  if (bx <= 1){                                // WcET halves
    for (int i = bx*960 + t; i < (bx+1)*960; i += 256){
      int n=i/10, f=i%10; float s=0.f;
      for(int e=0;e<64;e++) s += embed_W[f*64+e]*enc_Wih[n*64+e];
      WcET[i]=s;
    }
  } else if (bx == 2){
    for (int i = t; i < 384; i += 256){ int n=i/2, c=i%2; float s=0.f;
      for(int e=0;e<64;e++) s += proj_W[c*64+e]*dec_Wih[n*64+e]; WcDT[i]=s; }
    for (int n = t; n < 192; n += 256){
      float s=enc_bih[n]; for(int e=0;e<64;e++) s += embed_b[e]*enc_Wih[n*64+e]; bcE[n]=s;
      float d=dec_bih[n]; for(int e=0;e<64;e++) d += proj_b[e]*dec_Wih[n*64+e]; bcD[n]=d; }
    __syncthreads();
    for (int n = t; n < 128; n += 256){ brzE[n]=bcE[n]+enc_bhh[n]; brzD[n]=bcD[n]+dec_bhh[n]; }
  } else if (bx == 3){
    for (int i = t; i < 640; i += 256){ int f=i/64, n=i%64; float s=0.f;
      for(int e=0;e<64;e++) s += embed_W[f*64+e]*gat_W[e*64+n]; EG[i]=s; }
    for (int n = t; n < 64; n += 256){ float s=0.f;
      for(int e=0;e<64;e++) s += embed_b[e]*gat_W[e*64+n]; ebg0[n]=s; }
    __syncthreads();
    for (int f = t; f < 10; f += 256){ float s=0.f, d=0.f;
      for(int n=0;n<64;n++){ s += EG[f*64+n]*gat_as[n]; d += EG[f*64+n]*gat_ad[n]; }
      egs[f]=s; egd[f]=d; }
    if (t == 0){ float s=0.f, d=0.f;
      for(int n=0;n<64;n++){ s += ebg0[n]*gat_as[n]; d += ebg0[n]*gat_ad[n]; }
      c6[0]=s; c6[1]=d; }
  }
}

// ---------- setup stage 2: fragment build (64 blocks, gtid-stride) ----------
__global__ void setup_frag(
    const float* __restrict__ enc_Whh, const float* __restrict__ enc_bhh,
    const float* __restrict__ dec_Whh, const float* __restrict__ dec_bhh,
    const float* __restrict__ gat_b,
    const float* __restrict__ out_W1,  const float* __restrict__ out_W2,
    const float* __restrict__ conf_W1, const float* __restrict__ conf_W2,
    short* __restrict__ wsb)
{
  const float* wsf  = (const float*)(wsb) + 26880;
  const float* WcET = wsf;        const float* WcDT = wsf+1920;
  const float* bcE  = wsf+2304;   const float* bcD  = wsf+2496;
  const float* brzE = wsf+2688;   const float* brzD = wsf+2816;
  const float* EG   = wsf+2944;   const float* ebg0 = wsf+3584;
  const float* egs  = wsf+3648;   const float* egd  = wsf+3658;
  const float* c6   = wsf+3668;
  const int gt = blockIdx.x*256 + threadIdx.x;
  const int gs = gridDim.x*256;

  for (int i = gt; i < 18432; i += gs){           // B1E
    int nt=i/1536, r=i%1536, kt=r>>9, r2=r&511, lane=r2>>3, j=r2&7;
    int k=kt*32+(lane>>4)*8+j, n=nt*16+(lane&15);
    float v=0.f;
    if (k < 64) v = enc_Whh[n*64+k];
    else if (k < 74){ if (n < 128) v = WcET[n*10+(k-64)]; }
    else if (k == 74) v = (n < 128) ? brzE[n] : enc_bhh[n];
    wsb[i]=f2b(v);
  }
  for (int i = gt; i < 2048; i += gs){            // B2E
    int nt=i>>9, r2=i&511, lane=r2>>3, j=r2&7;
    int k=64+(lane>>4)*8+j, n=128+nt*16+(lane&15);
    float v=0.f;
    if (k < 74) v = WcET[n*10+(k-64)];
    else if (k == 74) v = bcE[n];
    wsb[18432+i]=f2b(v);
  }
  for (int i = gt; i < 18432; i += gs){           // B1D
    int nt=i/1536, r=i%1536, kt=r>>9, r2=r&511, lane=r2>>3, j=r2&7;
    int k=kt*32+(lane>>4)*8+j, n=nt*16+(lane&15);
    float v=0.f;
    if (k < 64) v = dec_Whh[n*64+k];
    else if (k < 66){ if (n < 128) v = WcDT[n*2+(k-64)]; }
    else if (k == 66) v = (n < 128) ? brzD[n] : dec_bhh[n];
    wsb[20480+i]=f2b(v);
  }
  for (int i = gt; i < 2048; i += gs){            // B2D
    int nt=i>>9, r2=i&511, lane=r2>>3, j=r2&7;
    int k=64+(lane>>4)*8+j, n=128+nt*16+(lane&15);
    float v=0.f;
    if (k < 66) v = WcDT[n*2+(k-64)];
    else if (k == 66) v = bcD[n];
    wsb[38912+i]=f2b(v);
  }
  for (int i = gt; i < 2560; i += gs){            // B3
    int nt=i>>9, r2=i&511, lane=r2>>3, j=r2&7;
    int k=64+(lane>>4)*8+j, n=nt*16+(lane&15);
    float v=0.f;
    if (k < 74){ int f=k-64;
      if (n < 64) v = EG[f*64+n]; else if (n == 64) v = egs[f]; else if (n == 65) v = egd[f];
    } else if (k == 74){
      if (n < 64) v = ebg0[n]+gat_b[n]; else if (n == 64) v = c6[0]; else if (n == 65) v = c6[1];
    }
    wsb[40960+i]=f2b(v);
  }
  for (int i = gt; i < 4096; i += gs){            // BW1 / BC1
    int nt=i>>10, r=i&1023, kt=r>>9, r2=r&511, lane=r2>>3, j=r2&7;
    int k=kt*32+(lane>>4)*8+j, n=nt*16+(lane&15);
    wsb[43520+i]=f2b(out_W1 [k*64+n]);
    wsb[48640+i]=f2b(conf_W1[k*64+n]);
  }
  for (int i = gt; i < 1024; i += gs){            // BW2 / BC2
    int kt=i>>9, r2=i&511, lane=r2>>3, j=r2&7;
    int k=kt*32+(lane>>4)*8+j, n=lane&15;
    wsb[47616+i]=f2b(n<10 ? out_W2 [k*10+n] : 0.f);
    wsb[52736+i]=f2b(n<5  ? conf_W2[k*5 +n] : 0.f);
  }
}

// One GRU step on a wave's private 16-row tile. kt0/kt1 (h-part) B frags from
// LDS; kt2 + B2 (x+bias part, block-uniform) from global (L1/L2-hot).
// No __syncthreads needed: all LDS traffic is wave-private; per-wave DS ops
// execute in order; wave_barrier pins compiler ordering.
__device__ __forceinline__ void gru_mfma_step(const short* BsL, const short* __restrict__ Bg,
    short* hS, float (&hcd)[4][4], bf16x8 af2, int wid, int lane)
{
  const int g = lane>>4, l15 = lane&15;
  const int arow = wid*16 + l15;
  const int sw = arow & 7;
  bf16x8 af0 = *(const bf16x8*)&hS[arow*64 + (((0+g) ^ sw)<<3)];
  bf16x8 af1 = *(const bf16x8*)&hS[arow*64 + (((4+g) ^ sw)<<3)];
  f32x4 acc[12];
  #pragma unroll
  for (int nt = 0; nt < 12; nt++){
    f32x4 a = {0.f,0.f,0.f,0.f};
    a = MFMA16(af0, *(const bf16x8*)&BsL[(nt*2+0)*512 + lane*8], a);
    a = MFMA16(af1, *(const bf16x8*)&BsL[(nt*2+1)*512 + lane*8], a);
    a = MFMA16(af2, *(const bf16x8*)&Bg[(nt*3+2)*512 + lane*8], a);
    acc[nt] = a;
  }
  f32x4 accx[4];
  #pragma unroll
  for (int nt = 0; nt < 4; nt++){
    f32x4 a = {0.f,0.f,0.f,0.f};
    accx[nt] = MFMA16(af2, *(const bf16x8*)&Bg[18432 + nt*512 + lane*8], a);
  }
  #pragma unroll
  for (int nt = 0; nt < 4; nt++){
    #pragma unroll
    for (int j = 0; j < 4; j++){
      float r  = sigm(acc[nt][j]);
      float z  = sigm(acc[nt+4][j]);
      float ng = tanh_f(accx[nt][j] + r*acc[nt+8][j]);
      float hn = (1.f - z)*ng + z*hcd[nt][j];
      hcd[nt][j] = hn;
      hS[hswz(wid*16 + 4*g + j, nt*16 + l15)] = f2b(hn);
    }
  }
  __builtin_amdgcn_wave_barrier();
}

__global__ __launch_bounds__(256, 3) void model_kernel(
    const float* __restrict__ x, const short* __restrict__ wsb,
    const float* __restrict__ out_b1, const float* __restrict__ out_b2,
    const float* __restrict__ conf_b1, const float* __restrict__ conf_b2,
    float* __restrict__ traj, float* __restrict__ conf, int B)
{
  __shared__ __align__(16) short Bs[12288];   // GRU B1 kt0/kt1 (h-part) only
  __shared__ __align__(16) short hS[4096];    // h tile, bf16 swizzled
  __shared__ __align__(16) short sS[4096];    // xl / relu-s overlay
  __shared__ float xyS[128];
  __shared__ float asdS[128];
  __shared__ float maskS[64];

  const int tid = threadIdx.x;
  const int wid = tid>>6, lane = tid&63;
  const int g = lane>>4, l15 = lane&15;
  const int BN = B*NNODE;
  const int br0 = blockIdx.x*60;
  const int arow = wid*16 + l15;
  const short ONE = 0x3F80;

  float b1r[4], cb1r[4];
  #pragma unroll
  for (int nt = 0; nt < 4; nt++){ b1r[nt]=out_b1[nt*16+l15]; cb1r[nt]=conf_b1[nt*16+l15]; }
  const float b2r  = out_b2 [l15<10 ? l15 : 0];
  const float cb2r = conf_b2[l15<5  ? l15 : 0];

  int growA = br0 + arow; if (growA > BN-1) growA = BN-1;
  const float* xrow = x + (size_t)(growA/5)*250 + (growA%5)*10;

  // copy enc B1 kt0/kt1 -> LDS (remap (nt*3+kt) -> (nt*2+kt)); zero hS
  for (int i = tid; i < 1536; i += 256){
    int f = i>>6, e = i&63, nt = f>>1, kt = f&1;
    ((int4*)Bs)[f*64 + e] = ((const int4*)wsb)[(nt*3+kt)*64 + e];
  }
  for (int i = tid; i < 4096; i += 256) hS[i] = 0;
  float hcd[4][4];
  #pragma unroll
  for (int a1=0;a1<4;a1++){
    #pragma unroll
    for (int a2=0;a2<4;a2++) hcd[a1][a2]=0.f;
  }
  __syncthreads();

  // ---------------- GRU encoder (no cross-wave deps -> no barriers) -------
  for (int t = 0; t < TIN; t++){
    bf16x8 af2 = {0,0,0,0,0,0,0,0};
    if (g == 0){
      const float2* p = (const float2*)(xrow + t*50);
      float2 v0=p[0], v1=p[1], v2=p[2], v3=p[3];
      af2[0]=f2b(v0.x); af2[1]=f2b(v0.y); af2[2]=f2b(v1.x); af2[3]=f2b(v1.y);
      af2[4]=f2b(v2.x); af2[5]=f2b(v2.y); af2[6]=f2b(v3.x); af2[7]=f2b(v3.y);
    } else if (g == 1){
      const float2* p = (const float2*)(xrow + t*50 + 8);
      float2 v4=p[0];
      af2[0]=f2b(v4.x); af2[1]=f2b(v4.y); af2[2]=ONE;
    }
    gru_mfma_step(Bs, wsb, hS, hcd, af2, wid, lane);
  }

  // ---------------- GAT ----------------
  {
    bf16x8 af2 = {0,0,0,0,0,0,0,0};
    if (g == 0){
      const float2* p = (const float2*)(xrow + 4*50);
      float2 v0=p[0], v1=p[1], v2=p[2], v3=p[3];
      af2[0]=f2b(v0.x); af2[1]=f2b(v0.y); af2[2]=f2b(v1.x); af2[3]=f2b(v1.y);
      af2[4]=f2b(v2.x); af2[5]=f2b(v2.y); af2[6]=f2b(v3.x); af2[7]=f2b(v3.y);
      float msum = v0.x+v0.y+v1.x+v1.y+v2.x+v2.y;
      maskS[arow] = (msum != 0.f) ? 1.f : 0.f;
      xyS[arow*2]   = v0.x;
      xyS[arow*2+1] = v0.y;
    } else if (g == 1){
      const float2* p = (const float2*)(xrow + 4*50 + 8);
      float2 v4=p[0];
      af2[0]=f2b(v4.x); af2[1]=f2b(v4.y); af2[2]=ONE;
    }
    #pragma unroll
    for (int nt = 0; nt < 5; nt++){
      f32x4 a = {0.f,0.f,0.f,0.f};
      a = MFMA16(af2, *(const bf16x8*)(wsb + 40960 + nt*512 + lane*8), a);
      if (nt < 4){
        #pragma unroll
        for (int j = 0; j < 4; j++)
          sS[(wid*16 + 4*g + j)*64 + nt*16 + l15] = f2b(a[j]);   // xl plain layout
      } else if (l15 < 2){
        #pragma unroll
        for (int j = 0; j < 4; j++)
          asdS[(wid*16 + 4*g + j)*2 + l15] = a[j];               // a_s / a_d
      }
    }
  }
  __syncthreads();                                   // cross-wave: aggregation
  {   // aggregation: 4 threads per dst row, 16 cols each (wave-aligned rows)
    int dst = tid >> 2, cb = tid & 3;
    if (dst < 60){
      int nd = dst % 5, bas = dst - nd;
      float ad  = asdS[dst*2+1];
      float mkD = maskS[dst];
      float al[5], mx = -1e30f;
      #pragma unroll
      for (int i = 0; i < 5; i++){
        float a = asdS[(bas+i)*2] + ad;
        a = (a > 0.f) ? a : 0.2f*a;
        bool valid = (i == nd) || (maskS[bas+i] != 0.f && mkD != 0.f);
        al[i] = valid ? a : -1e30f;
        mx = fmaxf(mx, al[i]);
      }
      float w5[5], es = 0.f;
      #pragma unroll
      for (int i = 0; i < 5; i++){ float e = (al[i] > -1e29f) ? __expf(al[i]-mx) : 0.f; w5[i]=e; es+=e; }
      float rs = fastrcp(es);
      #pragma unroll
      for (int i = 0; i < 5; i++) w5[i] *= rs;
      for (int cc = 0; cc < 16; cc++){
        int c = cb*16 + cc;
        float agg = 0.f;
        #pragma unroll
        for (int i = 0; i < 5; i++) agg += w5[i]*b2f(sS[(bas+i)*64 + c]);
        int hi = hswz(dst, c);
        hS[hi] = f2b(b2f(hS[hi]) + agg);       // h_final = h_enc + gat_out
      }
    }
  }
  __syncthreads();                                   // aggregation done
  #pragma unroll
  for (int nt = 0; nt < 4; nt++){
    #pragma unroll
    for (int j = 0; j < 4; j++)
      hcd[nt][j] = b2f(hS[hswz(wid*16+4*g+j, nt*16+l15)]);
  }

  // ---------------- confidence head (wave-private) ----------------
  {
    const int sw = arow & 7;
    bf16x8 hf0 = *(const bf16x8*)&hS[arow*64 + (((0+g) ^ sw)<<3)];
    bf16x8 hf1 = *(const bf16x8*)&hS[arow*64 + (((4+g) ^ sw)<<3)];
    #pragma unroll
    for (int nt = 0; nt < 4; nt++){
      f32x4 a = {0.f,0.f,0.f,0.f};
      a = MFMA16(hf0, *(const bf16x8*)(wsb + 48640 + (nt*2+0)*512 + lane*8), a);
      a = MFMA16(hf1, *(const bf16x8*)(wsb + 48640 + (nt*2+1)*512 + lane*8), a);
      #pragma unroll
      for (int j = 0; j < 4; j++)
        sS[hswz(wid*16+4*g+j, nt*16+l15)] = f2b(fmaxf(a[j] + cb1r[nt], 0.f));
    }
    __builtin_amdgcn_wave_barrier();
    bf16x8 sf0 = *(const bf16x8*)&sS[arow*64 + (((0+g) ^ sw)<<3)];
    bf16x8 sf1 = *(const bf16x8*)&sS[arow*64 + (((4+g) ^ sw)<<3)];
    f32x4 a = {0.f,0.f,0.f,0.f};
    a = MFMA16(sf0, *(const bf16x8*)(wsb + 52736 + 0*512 + lane*8), a);
    a = MFMA16(sf1, *(const bf16x8*)(wsb + 52736 + 1*512 + lane*8), a);
    #pragma unroll
    for (int j = 0; j < 4; j++){
      float my = a[j] + cb2r;
      float v0 = __shfl(my, (lane&48)+0, 64);
      float v1 = __shfl(my, (lane&48)+1, 64);
      float v2 = __shfl(my, (lane&48)+2, 64);
      float v3 = __shfl(my, (lane&48)+3, 64);
      float v4 = __shfl(my, (lane&48)+4, 64);
      float mx = fmaxf(fmaxf(fmaxf(v0,v1),fmaxf(v2,v3)),v4);
      float es = __expf(v0-mx)+__expf(v1-mx)+__expf(v2-mx)+__expf(v3-mx)+__expf(v4-mx);
      int lrow = wid*16 + 4*g + j;
      int gr = br0 + lrow;
      if (l15 < 5 && lrow < 60 && gr < BN){
        int samp = gr/5, node = gr - samp*5;
        conf[((size_t)samp*NMODE + l15)*NNODE + node] = __expf(my-mx)*fastrcp(es);
      }
    }
  }

  // ---------------- reload decoder B (kt0/kt1) ----------------
  for (int i = tid; i < 1536; i += 256){
    int f = i>>6, e = i&63, nt = f>>1, kt = f&1;
    ((int4*)Bs)[f*64 + e] = ((const int4*)(wsb + 20480))[(nt*3+kt)*64 + e];
  }
  __syncthreads();                                   // Bs ready for all waves

  // ---------------- GRUCell decoder (wave-private) ----------------
  const short* Bgd = wsb + 20480;
  for (int t = 0; t < TOUT; t++){
    bf16x8 af2 = {0,0,0,0,0,0,0,0};
    if (g == 0){
      af2[0] = f2b(xyS[arow*2]);
      af2[1] = f2b(xyS[arow*2+1]);
      af2[2] = ONE;
    }
    gru_mfma_step(Bs, Bgd, hS, hcd, af2, wid, lane);

    const int sw = arow & 7;
    bf16x8 hf0 = *(const bf16x8*)&hS[arow*64 + (((0+g) ^ sw)<<3)];
    bf16x8 hf1 = *(const bf16x8*)&hS[arow*64 + (((4+g) ^ sw)<<3)];
    #pragma unroll
    for (int nt = 0; nt < 4; nt++){
      f32x4 a = {0.f,0.f,0.f,0.f};
      a = MFMA16(hf0, *(const bf16x8*)(wsb + 43520 + (nt*2+0)*512 + lane*8), a);
      a = MFMA16(hf1, *(const bf16x8*)(wsb + 43520 + (nt*2+1)*512 + lane*8), a);
      #pragma unroll
      for (int j = 0; j < 4; j++)
        sS[hswz(wid*16+4*g+j, nt*16+l15)] = f2b(fmaxf(a[j] + b1r[nt], 0.f));
    }
    __builtin_amdgcn_wave_barrier();
    bf16x8 sf0 = *(const bf16x8*)&sS[arow*64 + (((0+g) ^ sw)<<3)];
    bf16x8 sf1 = *(const bf16x8*)&sS[arow*64 + (((4+g) ^ sw)<<3)];
    f32x4 oo = {0.f,0.f,0.f,0.f};
    oo = MFMA16(sf0, *(const bf16x8*)(wsb + 47616 + 0*512 + lane*8), oo);
    oo = MFMA16(sf1, *(const bf16x8*)(wsb + 47616 + 1*512 + lane*8), oo);
    #pragma unroll
    for (int j = 0; j < 4; j++){
      float ov = oo[j] + b2r;
      int lrow = wid*16 + 4*g + j;
      int gr = br0 + lrow;
      if (l15 < 10 && lrow < 60 && gr < BN){
        int samp = gr/5, node = gr - samp*5;
        int cc = (l15 >= 5) ? 1 : 0;
        int m = l15 - 5*cc;
        traj[((size_t)(samp*NMODE + m)*NNODE + node)*(TOUT*2) + t*2 + cc] = ov;
      }
      if (l15 == 0) xyS[lrow*2]   = ov;    // mode-0 x fed back (own wave rows)
      if (l15 == 5) xyS[lrow*2+1] = ov;
    }
    __builtin_amdgcn_wave_barrier();
  }
}

extern "C" void kernel_launch(void* const* d_in, const int* in_sizes, int n_in,
                              void* d_out, int out_size, void* d_ws, size_t ws_size,
                              hipStream_t stream)
{
  const float* x           = (const float*)d_in[0];
  const float* embed_W     = (const float*)d_in[1];
  const float* embed_b     = (const float*)d_in[2];
  const float* gat_W       = (const float*)d_in[3];
  const float* gat_att_src = (const float*)d_in[4];
  const float* gat_att_dst = (const float*)d_in[5];
  const float* gat_b       = (const float*)d_in[6];
  const float* enc_Wih     = (const float*)d_in[7];
  const float* enc_Whh     = (const float*)d_in[8];
  const float* enc_bih     = (const float*)d_in[9];
  const float* enc_bhh     = (const float*)d_in[10];
  const float* dec_Wih     = (const float*)d_in[11];
  const float* dec_Whh     = (const float*)d_in[12];
  const float* dec_bih     = (const float*)d_in[13];
  const float* dec_bhh     = (const float*)d_in[14];
  const float* out_W1      = (const float*)d_in[15];
  const float* out_b1      = (const float*)d_in[16];
  const float* out_W2      = (const float*)d_in[17];
  const float* out_b2      = (const float*)d_in[18];
  const float* proj_W      = (const float*)d_in[19];
  const float* proj_b      = (const float*)d_in[20];
  const float* conf_W1     = (const float*)d_in[21];
  const float* conf_b1     = (const float*)d_in[22];
  const float* conf_W2     = (const float*)d_in[23];
  const float* conf_b2     = (const float*)d_in[24];

  const int B = in_sizes[0] / (TIN*NNODE*FD);
  const int BN = B*NNODE;
  short* wsb = (short*)d_ws;
  float* traj = (float*)d_out;
  float* conf = traj + (size_t)B*NMODE*NNODE*TOUT*2;

  setup_fold<<<4, 256, 0, stream>>>(embed_W, embed_b, enc_Wih, enc_bih,
                                    dec_Wih, dec_bih, proj_W, proj_b,
                                    gat_W, gat_att_src, gat_att_dst,
                                    enc_bhh, dec_bhh, wsb);
  setup_frag<<<64, 256, 0, stream>>>(enc_Whh, enc_bhh, dec_Whh, dec_bhh, gat_b,
                                     out_W1, out_W2, conf_W1, conf_W2, wsb);

  const int blocks = (BN + 59)/60;
  model_kernel<<<blocks, 256, 0, stream>>>(x, wsb, out_b1, out_b2, conf_b1, conf_b2,
                                           traj, conf, B);
}

// Round 8
// 529.516 us; speedup vs baseline: 1.3251x; 1.3251x over previous
//
#include <hip/hip_runtime.h>

#define HDIM 64
#define NMODE 5
#define TOUT 6
#define TIN 5
#define NNODE 5
#define FD 10
#define ROWS 128      // hS/sS rows per block (8 waves x 16)
#define ACTR 120      // active rows per block (24 samples x 5 nodes)

typedef short bf16x8 __attribute__((ext_vector_type(8)));
typedef float f32x4 __attribute__((ext_vector_type(4)));

#define MFMA16(A,B,C) __builtin_amdgcn_mfma_f32_16x16x32_bf16((A),(B),(C),0,0,0)

// ---------------- ws layout (identical to round 5) ----------------
//   B1E @ 0      len 18432  (NT=12, KT=3)  enc: [Whh | WcET | brz-const]
//   B2E @ 18432  len 2048   enc n-gate x-part
//   B1D @ 20480  len 18432  dec
//   B2D @ 38912  len 2048
//   B3  @ 40960  len 2560   GAT fold
//   BW1 @ 43520  len 4096   out_W1
//   BW2 @ 47616  len 1024   out_W2
//   BC1 @ 48640  len 4096   conf_W1
//   BC2 @ 52736  len 1024   conf_W2
// f32 scratch at float-index 26880.
// Fragment order: ((nt*KT+kt)*64 + lane)*8 + j ; k = kt*32+(lane>>4)*8+j,
// n = nt*16+(lane&15). A built with the same map -> permutation cancels.

__device__ __forceinline__ float fastrcp(float x){ return __builtin_amdgcn_rcpf(x); }
__device__ __forceinline__ float sigm(float x){ return fastrcp(1.f + __expf(-x)); }
__device__ __forceinline__ float tanh_f(float x){ return 2.f*fastrcp(1.f + __expf(-2.f*x)) - 1.f; }

__device__ __forceinline__ short f2b(float f){            // f32 -> bf16 RNE
  unsigned u = __float_as_uint(f);
  unsigned r = (u + 0x7FFFu + ((u >> 16) & 1u)) >> 16;
  return (short)r;
}
__device__ __forceinline__ float b2f(short s){
  return __uint_as_float(((unsigned)(unsigned short)s) << 16);
}
__device__ __forceinline__ int hswz(int row, int col){
  return row*64 + ((((col>>3) ^ (row&7)))<<3) + (col&7);
}

// ---------- setup stage 1: weight folds into f32 scratch (4 blocks) ----------
__global__ void setup_fold(
    const float* __restrict__ embed_W, const float* __restrict__ embed_b,
    const float* __restrict__ enc_Wih, const float* __restrict__ enc_bih,
    const float* __restrict__ dec_Wih, const float* __restrict__ dec_bih,
    const float* __restrict__ proj_W,  const float* __restrict__ proj_b,
    const float* __restrict__ gat_W,   const float* __restrict__ gat_as,
    const float* __restrict__ gat_ad,
    const float* __restrict__ enc_bhh, const float* __restrict__ dec_bhh,
    short* __restrict__ wsb)
{
  float* wsf  = (float*)(wsb) + 26880;
  float* WcET = wsf;        float* WcDT = wsf+1920;
  float* bcE  = wsf+2304;   float* bcD  = wsf+2496;
  float* brzE = wsf+2688;   float* brzD = wsf+2816;
  float* EG   = wsf+2944;   float* ebg0 = wsf+3584;
  float* egs  = wsf+3648;   float* egd  = wsf+3658;
  float* c6   = wsf+3668;
  const int t = threadIdx.x, bx = blockIdx.x;

  if (bx <= 1){                                // WcET halves
    for (int i = bx*960 + t; i < (bx+1)*960; i += 256){
      int n=i/10, f=i%10; float s=0.f;
      for(int e=0;e<64;e++) s += embed_W[f*64+e]*enc_Wih[n*64+e];
      WcET[i]=s;
    }
  } else if (bx == 2){
    for (int i = t; i < 384; i += 256){ int n=i/2, c=i%2; float s=0.f;
      for(int e=0;e<64;e++) s += proj_W[c*64+e]*dec_Wih[n*64+e]; WcDT[i]=s; }
    for (int n = t; n < 192; n += 256){
      float s=enc_bih[n]; for(int e=0;e<64;e++) s += embed_b[e]*enc_Wih[n*64+e]; bcE[n]=s;
      float d=dec_bih[n]; for(int e=0;e<64;e++) d += proj_b[e]*dec_Wih[n*64+e]; bcD[n]=d; }
    __syncthreads();
    for (int n = t; n < 128; n += 256){ brzE[n]=bcE[n]+enc_bhh[n]; brzD[n]=bcD[n]+dec_bhh[n]; }
  } else if (bx == 3){
    for (int i = t; i < 640; i += 256){ int f=i/64, n=i%64; float s=0.f;
      for(int e=0;e<64;e++) s += embed_W[f*64+e]*gat_W[e*64+n]; EG[i]=s; }
    for (int n = t; n < 64; n += 256){ float s=0.f;
      for(int e=0;e<64;e++) s += embed_b[e]*gat_W[e*64+n]; ebg0[n]=s; }
    __syncthreads();
    for (int f = t; f < 10; f += 256){ float s=0.f, d=0.f;
      for(int n=0;n<64;n++){ s += EG[f*64+n]*gat_as[n]; d += EG[f*64+n]*gat_ad[n]; }
      egs[f]=s; egd[f]=d; }
    if (t == 0){ float s=0.f, d=0.f;
      for(int n=0;n<64;n++){ s += ebg0[n]*gat_as[n]; d += ebg0[n]*gat_ad[n]; }
      c6[0]=s; c6[1]=d; }
  }
}

// ---------- setup stage 2: fragment build (64 blocks, gtid-stride) ----------
__global__ void setup_frag(
    const float* __restrict__ enc_Whh, const float* __restrict__ enc_bhh,
    const float* __restrict__ dec_Whh, const float* __restrict__ dec_bhh,
    const float* __restrict__ gat_b,
    const float* __restrict__ out_W1,  const float* __restrict__ out_W2,
    const float* __restrict__ conf_W1, const float* __restrict__ conf_W2,
    short* __restrict__ wsb)
{
  const float* wsf  = (const float*)(wsb) + 26880;
  const float* WcET = wsf;        const float* WcDT = wsf+1920;
  const float* bcE  = wsf+2304;   const float* bcD  = wsf+2496;
  const float* brzE = wsf+2688;   const float* brzD = wsf+2816;
  const float* EG   = wsf+2944;   const float* ebg0 = wsf+3584;
  const float* egs  = wsf+3648;   const float* egd  = wsf+3658;
  const float* c6   = wsf+3668;
  const int gt = blockIdx.x*256 + threadIdx.x;
  const int gs = gridDim.x*256;

  for (int i = gt; i < 18432; i += gs){           // B1E
    int nt=i/1536, r=i%1536, kt=r>>9, r2=r&511, lane=r2>>3, j=r2&7;
    int k=kt*32+(lane>>4)*8+j, n=nt*16+(lane&15);
    float v=0.f;
    if (k < 64) v = enc_Whh[n*64+k];
    else if (k < 74){ if (n < 128) v = WcET[n*10+(k-64)]; }
    else if (k == 74) v = (n < 128) ? brzE[n] : enc_bhh[n];
    wsb[i]=f2b(v);
  }
  for (int i = gt; i < 2048; i += gs){            // B2E
    int nt=i>>9, r2=i&511, lane=r2>>3, j=r2&7;
    int k=64+(lane>>4)*8+j, n=128+nt*16+(lane&15);
    float v=0.f;
    if (k < 74) v = WcET[n*10+(k-64)];
    else if (k == 74) v = bcE[n];
    wsb[18432+i]=f2b(v);
  }
  for (int i = gt; i < 18432; i += gs){           // B1D
    int nt=i/1536, r=i%1536, kt=r>>9, r2=r&511, lane=r2>>3, j=r2&7;
    int k=kt*32+(lane>>4)*8+j, n=nt*16+(lane&15);
    float v=0.f;
    if (k < 64) v = dec_Whh[n*64+k];
    else if (k < 66){ if (n < 128) v = WcDT[n*2+(k-64)]; }
    else if (k == 66) v = (n < 128) ? brzD[n] : dec_bhh[n];
    wsb[20480+i]=f2b(v);
  }
  for (int i = gt; i < 2048; i += gs){            // B2D
    int nt=i>>9, r2=i&511, lane=r2>>3, j=r2&7;
    int k=64+(lane>>4)*8+j, n=128+nt*16+(lane&15);
    float v=0.f;
    if (k < 66) v = WcDT[n*2+(k-64)];
    else if (k == 66) v = bcD[n];
    wsb[38912+i]=f2b(v);
  }
  for (int i = gt; i < 2560; i += gs){            // B3
    int nt=i>>9, r2=i&511, lane=r2>>3, j=r2&7;
    int k=64+(lane>>4)*8+j, n=nt*16+(lane&15);
    float v=0.f;
    if (k < 74){ int f=k-64;
      if (n < 64) v = EG[f*64+n]; else if (n == 64) v = egs[f]; else if (n == 65) v = egd[f];
    } else if (k == 74){
      if (n < 64) v = ebg0[n]+gat_b[n]; else if (n == 64) v = c6[0]; else if (n == 65) v = c6[1];
    }
    wsb[40960+i]=f2b(v);
  }
  for (int i = gt; i < 4096; i += gs){            // BW1 / BC1
    int nt=i>>10, r=i&1023, kt=r>>9, r2=r&511, lane=r2>>3, j=r2&7;
    int k=kt*32+(lane>>4)*8+j, n=nt*16+(lane&15);
    wsb[43520+i]=f2b(out_W1 [k*64+n]);
    wsb[48640+i]=f2b(conf_W1[k*64+n]);
  }
  for (int i = gt; i < 1024; i += gs){            // BW2 / BC2
    int kt=i>>9, r2=i&511, lane=r2>>3, j=r2&7;
    int k=kt*32+(lane>>4)*8+j, n=lane&15;
    wsb[47616+i]=f2b(n<10 ? out_W2 [k*10+n] : 0.f);
    wsb[52736+i]=f2b(n<5  ? conf_W2[k*5 +n] : 0.f);
  }
}

// One GRU step on a wave's private 16-row tile. ALL GRU B fragments from LDS
// (round-6 lesson: per-step global B reads thrash L2 -> 585MB HBM fetch).
// Wave-private LDS traffic -> no cross-wave barrier; wave_barrier pins order.
__device__ __forceinline__ void gru_mfma_step(const short* Bs,
    short* hS, float (&hcd)[4][4], bf16x8 af2, int wid, int lane)
{
  const int g = lane>>4, l15 = lane&15;
  const int arow = wid*16 + l15;
  const int sw = arow & 7;
  bf16x8 af0 = *(const bf16x8*)&hS[arow*64 + (((0+g) ^ sw)<<3)];
  bf16x8 af1 = *(const bf16x8*)&hS[arow*64 + (((4+g) ^ sw)<<3)];
  f32x4 acc[12];
  #pragma unroll
  for (int nt = 0; nt < 12; nt++){
    f32x4 a = {0.f,0.f,0.f,0.f};
    a = MFMA16(af0, *(const bf16x8*)&Bs[(nt*3+0)*512 + lane*8], a);
    a = MFMA16(af1, *(const bf16x8*)&Bs[(nt*3+1)*512 + lane*8], a);
    a = MFMA16(af2, *(const bf16x8*)&Bs[(nt*3+2)*512 + lane*8], a);
    acc[nt] = a;
  }
  f32x4 accx[4];
  #pragma unroll
  for (int nt = 0; nt < 4; nt++){
    f32x4 a = {0.f,0.f,0.f,0.f};
    accx[nt] = MFMA16(af2, *(const bf16x8*)&Bs[18432 + nt*512 + lane*8], a);
  }
  #pragma unroll
  for (int nt = 0; nt < 4; nt++){
    #pragma unroll
    for (int j = 0; j < 4; j++){
      float r  = sigm(acc[nt][j]);
      float z  = sigm(acc[nt+4][j]);
      float ng = tanh_f(accx[nt][j] + r*acc[nt+8][j]);
      float hn = (1.f - z)*ng + z*hcd[nt][j];
      hcd[nt][j] = hn;
      hS[hswz(wid*16 + 4*g + j, nt*16 + l15)] = f2b(hn);
    }
  }
  __builtin_amdgcn_wave_barrier();
}

__global__ __launch_bounds__(512, 4) void model_kernel(
    const float* __restrict__ x, const short* __restrict__ wsb,
    const float* __restrict__ out_b1, const float* __restrict__ out_b2,
    const float* __restrict__ conf_b1, const float* __restrict__ conf_b2,
    float* __restrict__ traj, float* __restrict__ conf, int B)
{
  __shared__ __align__(16) short Bs[20480];       // full GRU B1+B2 (enc->dec)
  __shared__ __align__(16) short hS[ROWS*64];     // h tile, bf16 swizzled
  __shared__ __align__(16) short sS[ROWS*64];     // xl / relu-s overlay
  __shared__ float xyS[ROWS*2];
  __shared__ float asdS[ROWS*2];
  __shared__ float maskS[ROWS];

  const int tid = threadIdx.x;
  const int wid = tid>>6, lane = tid&63;
  const int g = lane>>4, l15 = lane&15;
  const int BN = B*NNODE;
  const int br0 = blockIdx.x*ACTR;
  const int arow = wid*16 + l15;
  const short ONE = 0x3F80;

  float b1r[4], cb1r[4];
  #pragma unroll
  for (int nt = 0; nt < 4; nt++){ b1r[nt]=out_b1[nt*16+l15]; cb1r[nt]=conf_b1[nt*16+l15]; }
  const float b2r  = out_b2 [l15<10 ? l15 : 0];
  const float cb2r = conf_b2[l15<5  ? l15 : 0];

  int growA = br0 + arow; if (growA > BN-1) growA = BN-1;
  const float* xrow = x + (size_t)(growA/5)*250 + (growA%5)*10;

  for (int i = tid; i < 2560; i += 512) ((int4*)Bs)[i] = ((const int4*)wsb)[i];
  for (int i = tid; i < ROWS*64; i += 512) hS[i] = 0;
  float hcd[4][4];
  #pragma unroll
  for (int a1=0;a1<4;a1++){
    #pragma unroll
    for (int a2=0;a2<4;a2++) hcd[a1][a2]=0.f;
  }
  __syncthreads();

  // ---------------- GRU encoder (wave-private; no barriers) ----------------
  for (int t = 0; t < TIN; t++){
    bf16x8 af2 = {0,0,0,0,0,0,0,0};
    if (g == 0){
      const float2* p = (const float2*)(xrow + t*50);
      float2 v0=p[0], v1=p[1], v2=p[2], v3=p[3];
      af2[0]=f2b(v0.x); af2[1]=f2b(v0.y); af2[2]=f2b(v1.x); af2[3]=f2b(v1.y);
      af2[4]=f2b(v2.x); af2[5]=f2b(v2.y); af2[6]=f2b(v3.x); af2[7]=f2b(v3.y);
    } else if (g == 1){
      const float2* p = (const float2*)(xrow + t*50 + 8);
      float2 v4=p[0];
      af2[0]=f2b(v4.x); af2[1]=f2b(v4.y); af2[2]=ONE;
    }
    gru_mfma_step(Bs, hS, hcd, af2, wid, lane);
  }

  // ---------------- GAT ----------------
  {
    bf16x8 af2 = {0,0,0,0,0,0,0,0};
    if (g == 0){
      const float2* p = (const float2*)(xrow + 4*50);
      float2 v0=p[0], v1=p[1], v2=p[2], v3=p[3];
      af2[0]=f2b(v0.x); af2[1]=f2b(v0.y); af2[2]=f2b(v1.x); af2[3]=f2b(v1.y);
      af2[4]=f2b(v2.x); af2[5]=f2b(v2.y); af2[6]=f2b(v3.x); af2[7]=f2b(v3.y);
      float msum = v0.x+v0.y+v1.x+v1.y+v2.x+v2.y;
      maskS[arow] = (msum != 0.f) ? 1.f : 0.f;
      xyS[arow*2]   = v0.x;
      xyS[arow*2+1] = v0.y;
    } else if (g == 1){
      const float2* p = (const float2*)(xrow + 4*50 + 8);
      float2 v4=p[0];
      af2[0]=f2b(v4.x); af2[1]=f2b(v4.y); af2[2]=ONE;
    }
    #pragma unroll
    for (int nt = 0; nt < 5; nt++){
      f32x4 a = {0.f,0.f,0.f,0.f};
      a = MFMA16(af2, *(const bf16x8*)(wsb + 40960 + nt*512 + lane*8), a);
      if (nt < 4){
        #pragma unroll
        for (int j = 0; j < 4; j++)
          sS[(wid*16 + 4*g + j)*64 + nt*16 + l15] = f2b(a[j]);   // xl plain layout
      } else if (l15 < 2){
        #pragma unroll
        for (int j = 0; j < 4; j++)
          asdS[(wid*16 + 4*g + j)*2 + l15] = a[j];               // a_s / a_d
      }
    }
  }
  __syncthreads();                                   // cross-wave: aggregation
  {   // aggregation: 4 threads per dst row, 16 cols each
    int dst = tid >> 2, cb = tid & 3;
    if (dst < ACTR){
      int nd = dst % 5, bas = dst - nd;
      float ad  = asdS[dst*2+1];
      float mkD = maskS[dst];
      float al[5], mx = -1e30f;
      #pragma unroll
      for (int i = 0; i < 5; i++){
        float a = asdS[(bas+i)*2] + ad;
        a = (a > 0.f) ? a : 0.2f*a;
        bool valid = (i == nd) || (maskS[bas+i] != 0.f && mkD != 0.f);
        al[i] = valid ? a : -1e30f;
        mx = fmaxf(mx, al[i]);
      }
      float w5[5], es = 0.f;
      #pragma unroll
      for (int i = 0; i < 5; i++){ float e = (al[i] > -1e29f) ? __expf(al[i]-mx) : 0.f; w5[i]=e; es+=e; }
      float rs = fastrcp(es);
      #pragma unroll
      for (int i = 0; i < 5; i++) w5[i] *= rs;
      for (int cc = 0; cc < 16; cc++){
        int c = cb*16 + cc;
        float agg = 0.f;
        #pragma unroll
        for (int i = 0; i < 5; i++) agg += w5[i]*b2f(sS[(bas+i)*64 + c]);
        int hi = hswz(dst, c);
        hS[hi] = f2b(b2f(hS[hi]) + agg);       // h_final = h_enc + gat_out
      }
    }
  }
  __syncthreads();                                   // aggregation done
  #pragma unroll
  for (int nt = 0; nt < 4; nt++){
    #pragma unroll
    for (int j = 0; j < 4; j++)
      hcd[nt][j] = b2f(hS[hswz(wid*16+4*g+j, nt*16+l15)]);
  }

  // ---------------- confidence head (wave-private) ----------------
  {
    const int sw = arow & 7;
    bf16x8 hf0 = *(const bf16x8*)&hS[arow*64 + (((0+g) ^ sw)<<3)];
    bf16x8 hf1 = *(const bf16x8*)&hS[arow*64 + (((4+g) ^ sw)<<3)];
    #pragma unroll
    for (int nt = 0; nt < 4; nt++){
      f32x4 a = {0.f,0.f,0.f,0.f};
      a = MFMA16(hf0, *(const bf16x8*)(wsb + 48640 + (nt*2+0)*512 + lane*8), a);
      a = MFMA16(hf1, *(const bf16x8*)(wsb + 48640 + (nt*2+1)*512 + lane*8), a);
      #pragma unroll
      for (int j = 0; j < 4; j++)
        sS[hswz(wid*16+4*g+j, nt*16+l15)] = f2b(fmaxf(a[j] + cb1r[nt], 0.f));
    }
    __builtin_amdgcn_wave_barrier();
    bf16x8 sf0 = *(const bf16x8*)&sS[arow*64 + (((0+g) ^ sw)<<3)];
    bf16x8 sf1 = *(const bf16x8*)&sS[arow*64 + (((4+g) ^ sw)<<3)];
    f32x4 a = {0.f,0.f,0.f,0.f};
    a = MFMA16(sf0, *(const bf16x8*)(wsb + 52736 + 0*512 + lane*8), a);
    a = MFMA16(sf1, *(const bf16x8*)(wsb + 52736 + 1*512 + lane*8), a);
    #pragma unroll
    for (int j = 0; j < 4; j++){
      float my = a[j] + cb2r;
      float v0 = __shfl(my, (lane&48)+0, 64);
      float v1 = __shfl(my, (lane&48)+1, 64);
      float v2 = __shfl(my, (lane&48)+2, 64);
      float v3 = __shfl(my, (lane&48)+3, 64);
      float v4 = __shfl(my, (lane&48)+4, 64);
      float mx = fmaxf(fmaxf(fmaxf(v0,v1),fmaxf(v2,v3)),v4);
      float es = __expf(v0-mx)+__expf(v1-mx)+__expf(v2-mx)+__expf(v3-mx)+__expf(v4-mx);
      int lrow = wid*16 + 4*g + j;
      int gr = br0 + lrow;
      if (l15 < 5 && lrow < ACTR && gr < BN){
        int samp = gr/5, node = gr - samp*5;
        conf[((size_t)samp*NMODE + l15)*NNODE + node] = __expf(my-mx)*fastrcp(es);
      }
    }
  }

  // ---------------- reload decoder B ----------------
  __syncthreads();                                   // all waves done with enc Bs
  for (int i = tid; i < 2560; i += 512) ((int4*)Bs)[i] = ((const int4*)(wsb + 20480))[i];
  __syncthreads();                                   // dec Bs ready

  // ---------------- GRUCell decoder (wave-private) ----------------
  for (int t = 0; t < TOUT; t++){
    bf16x8 af2 = {0,0,0,0,0,0,0,0};
    if (g == 0){
      af2[0] = f2b(xyS[arow*2]);
      af2[1] = f2b(xyS[arow*2+1]);
      af2[2] = ONE;
    }
    gru_mfma_step(Bs, hS, hcd, af2, wid, lane);

    const int sw = arow & 7;
    bf16x8 hf0 = *(const bf16x8*)&hS[arow*64 + (((0+g) ^ sw)<<3)];
    bf16x8 hf1 = *(const bf16x8*)&hS[arow*64 + (((4+g) ^ sw)<<3)];
    #pragma unroll
    for (int nt = 0; nt < 4; nt++){
      f32x4 a = {0.f,0.f,0.f,0.f};
      a = MFMA16(hf0, *(const bf16x8*)(wsb + 43520 + (nt*2+0)*512 + lane*8), a);
      a = MFMA16(hf1, *(const bf16x8*)(wsb + 43520 + (nt*2+1)*512 + lane*8), a);
      #pragma unroll
      for (int j = 0; j < 4; j++)
        sS[hswz(wid*16+4*g+j, nt*16+l15)] = f2b(fmaxf(a[j] + b1r[nt], 0.f));
    }
    __builtin_amdgcn_wave_barrier();
    bf16x8 sf0 = *(const bf16x8*)&sS[arow*64 + (((0+g) ^ sw)<<3)];
    bf16x8 sf1 = *(const bf16x8*)&sS[arow*64 + (((4+g) ^ sw)<<3)];
    f32x4 oo = {0.f,0.f,0.f,0.f};
    oo = MFMA16(sf0, *(const bf16x8*)(wsb + 47616 + 0*512 + lane*8), oo);
    oo = MFMA16(sf1, *(const bf16x8*)(wsb + 47616 + 1*512 + lane*8), oo);
    #pragma unroll
    for (int j = 0; j < 4; j++){
      float ov = oo[j] + b2r;
      int lrow = wid*16 + 4*g + j;
      int gr = br0 + lrow;
      if (l15 < 10 && lrow < ACTR && gr < BN){
        int samp = gr/5, node = gr - samp*5;
        int cc = (l15 >= 5) ? 1 : 0;
        int m = l15 - 5*cc;
        traj[((size_t)(samp*NMODE + m)*NNODE + node)*(TOUT*2) + t*2 + cc] = ov;
      }
      if (l15 == 0) xyS[lrow*2]   = ov;    // mode-0 x fed back (own wave rows)
      if (l15 == 5) xyS[lrow*2+1] = ov;
    }
    __builtin_amdgcn_wave_barrier();
  }
}

extern "C" void kernel_launch(void* const* d_in, const int* in_sizes, int n_in,
                              void* d_out, int out_size, void* d_ws, size_t ws_size,
                              hipStream_t stream)
{
  const float* x           = (const float*)d_in[0];
  const float* embed_W     = (const float*)d_in[1];
  const float* embed_b     = (const float*)d_in[2];
  const float* gat_W       = (const float*)d_in[3];
  const float* gat_att_src = (const float*)d_in[4];
  const float* gat_att_dst = (const float*)d_in[5];
  const float* gat_b       = (const float*)d_in[6];
  const float* enc_Wih     = (const float*)d_in[7];
  const float* enc_Whh     = (const float*)d_in[8];
  const float* enc_bih     = (const float*)d_in[9];
  const float* enc_bhh     = (const float*)d_in[10];
  const float* dec_Wih     = (const float*)d_in[11];
  const float* dec_Whh     = (const float*)d_in[12];
  const float* dec_bih     = (const float*)d_in[13];
  const float* dec_bhh     = (const float*)d_in[14];
  const float* out_W1      = (const float*)d_in[15];
  const float* out_b1      = (const float*)d_in[16];
  const float* out_W2      = (const float*)d_in[17];
  const float* out_b2      = (const float*)d_in[18];
  const float* proj_W      = (const float*)d_in[19];
  const float* proj_b      = (const float*)d_in[20];
  const float* conf_W1     = (const float*)d_in[21];
  const float* conf_b1     = (const float*)d_in[22];
  const float* conf_W2     = (const float*)d_in[23];
  const float* conf_b2     = (const float*)d_in[24];

  const int B = in_sizes[0] / (TIN*NNODE*FD);
  const int BN = B*NNODE;
  short* wsb = (short*)d_ws;
  float* traj = (float*)d_out;
  float* conf = traj + (size_t)B*NMODE*NNODE*TOUT*2;

  setup_fold<<<4, 256, 0, stream>>>(embed_W, embed_b, enc_Wih, enc_bih,
                                    dec_Wih, dec_bih, proj_W, proj_b,
                                    gat_W, gat_att_src, gat_att_dst,
                                    enc_bhh, dec_bhh, wsb);
  setup_frag<<<64, 256, 0, stream>>>(enc_Whh, enc_bhh, dec_Whh, dec_bhh, gat_b,
                                     out_W1, out_W2, conf_W1, conf_W2, wsb);

  const int blocks = (BN + ACTR - 1)/ACTR;
  model_kernel<<<blocks, 512, 0, stream>>>(x, wsb, out_b1, out_b2, conf_b1, conf_b2,
                                           traj, conf, B);
}

// Round 9
// 352.272 us; speedup vs baseline: 1.9918x; 1.5031x over previous
//
#include <hip/hip_runtime.h>

#define HDIM 64
#define NMODE 5
#define TOUT 6
#define TIN 5
#define NNODE 5
#define FD 10
#define ROWS 128      // hS/sS rows per block (8 waves x 16)
#define ACTR 120      // active rows per block (24 samples x 5 nodes)

typedef short bf16x8 __attribute__((ext_vector_type(8)));
typedef float f32x4 __attribute__((ext_vector_type(4)));

#define MFMA16(A,B,C) __builtin_amdgcn_mfma_f32_16x16x32_bf16((A),(B),(C),0,0,0)

// ---------------- ws layout (identical to round 5) ----------------
//   B1E @ 0      len 18432  (NT=12, KT=3)  enc: [Whh | WcET | brz-const]
//   B2E @ 18432  len 2048   enc n-gate x-part
//   B1D @ 20480  len 18432  dec
//   B2D @ 38912  len 2048
//   B3  @ 40960  len 2560   GAT fold
//   BW1 @ 43520  len 4096   out_W1
//   BW2 @ 47616  len 1024   out_W2
//   BC1 @ 48640  len 4096   conf_W1
//   BC2 @ 52736  len 1024   conf_W2
// f32 scratch at float-index 26880.
// Fragment order: ((nt*KT+kt)*64 + lane)*8 + j ; k = kt*32+(lane>>4)*8+j,
// n = nt*16+(lane&15). A built with the same map -> permutation cancels.
//
// NOTE on __launch_bounds__: (512, 2). Round-8 used (512, 4) and the 2nd arg
// acted as min BLOCKS/CU (CUDA semantics): 4 blk x 8 waves = 8 waves/SIMD ->
// VGPR cap 64 -> accumulator spill to scratch -> 718 MB HBM traffic. (512,2)
// gives cap 128 >= the ~124 this kernel needs; LDS caps us at 2 blocks/CU.

__device__ __forceinline__ float fastrcp(float x){ return __builtin_amdgcn_rcpf(x); }
__device__ __forceinline__ float sigm(float x){ return fastrcp(1.f + __expf(-x)); }
__device__ __forceinline__ float tanh_f(float x){ return 2.f*fastrcp(1.f + __expf(-2.f*x)) - 1.f; }

__device__ __forceinline__ short f2b(float f){            // f32 -> bf16 RNE
  unsigned u = __float_as_uint(f);
  unsigned r = (u + 0x7FFFu + ((u >> 16) & 1u)) >> 16;
  return (short)r;
}
__device__ __forceinline__ float b2f(short s){
  return __uint_as_float(((unsigned)(unsigned short)s) << 16);
}
__device__ __forceinline__ int hswz(int row, int col){
  return row*64 + ((((col>>3) ^ (row&7)))<<3) + (col&7);
}

// ---------- setup stage 1: weight folds into f32 scratch (4 blocks) ----------
__global__ void setup_fold(
    const float* __restrict__ embed_W, const float* __restrict__ embed_b,
    const float* __restrict__ enc_Wih, const float* __restrict__ enc_bih,
    const float* __restrict__ dec_Wih, const float* __restrict__ dec_bih,
    const float* __restrict__ proj_W,  const float* __restrict__ proj_b,
    const float* __restrict__ gat_W,   const float* __restrict__ gat_as,
    const float* __restrict__ gat_ad,
    const float* __restrict__ enc_bhh, const float* __restrict__ dec_bhh,
    short* __restrict__ wsb)
{
  float* wsf  = (float*)(wsb) + 26880;
  float* WcET = wsf;        float* WcDT = wsf+1920;
  float* bcE  = wsf+2304;   float* bcD  = wsf+2496;
  float* brzE = wsf+2688;   float* brzD = wsf+2816;
  float* EG   = wsf+2944;   float* ebg0 = wsf+3584;
  float* egs  = wsf+3648;   float* egd  = wsf+3658;
  float* c6   = wsf+3668;
  const int t = threadIdx.x, bx = blockIdx.x;

  if (bx <= 1){                                // WcET halves
    for (int i = bx*960 + t; i < (bx+1)*960; i += 256){
      int n=i/10, f=i%10; float s=0.f;
      for(int e=0;e<64;e++) s += embed_W[f*64+e]*enc_Wih[n*64+e];
      WcET[i]=s;
    }
  } else if (bx == 2){
    for (int i = t; i < 384; i += 256){ int n=i/2, c=i%2; float s=0.f;
      for(int e=0;e<64;e++) s += proj_W[c*64+e]*dec_Wih[n*64+e]; WcDT[i]=s; }
    for (int n = t; n < 192; n += 256){
      float s=enc_bih[n]; for(int e=0;e<64;e++) s += embed_b[e]*enc_Wih[n*64+e]; bcE[n]=s;
      float d=dec_bih[n]; for(int e=0;e<64;e++) d += proj_b[e]*dec_Wih[n*64+e]; bcD[n]=d; }
    __syncthreads();
    for (int n = t; n < 128; n += 256){ brzE[n]=bcE[n]+enc_bhh[n]; brzD[n]=bcD[n]+dec_bhh[n]; }
  } else if (bx == 3){
    for (int i = t; i < 640; i += 256){ int f=i/64, n=i%64; float s=0.f;
      for(int e=0;e<64;e++) s += embed_W[f*64+e]*gat_W[e*64+n]; EG[i]=s; }
    for (int n = t; n < 64; n += 256){ float s=0.f;
      for(int e=0;e<64;e++) s += embed_b[e]*gat_W[e*64+n]; ebg0[n]=s; }
    __syncthreads();
    for (int f = t; f < 10; f += 256){ float s=0.f, d=0.f;
      for(int n=0;n<64;n++){ s += EG[f*64+n]*gat_as[n]; d += EG[f*64+n]*gat_ad[n]; }
      egs[f]=s; egd[f]=d; }
    if (t == 0){ float s=0.f, d=0.f;
      for(int n=0;n<64;n++){ s += ebg0[n]*gat_as[n]; d += ebg0[n]*gat_ad[n]; }
      c6[0]=s; c6[1]=d; }
  }
}

// ---------- setup stage 2: fragment build (64 blocks, gtid-stride) ----------
__global__ void setup_frag(
    const float* __restrict__ enc_Whh, const float* __restrict__ enc_bhh,
    const float* __restrict__ dec_Whh, const float* __restrict__ dec_bhh,
    const float* __restrict__ gat_b,
    const float* __restrict__ out_W1,  const float* __restrict__ out_W2,
    const float* __restrict__ conf_W1, const float* __restrict__ conf_W2,
    short* __restrict__ wsb)
{
  const float* wsf  = (const float*)(wsb) + 26880;
  const float* WcET = wsf;        const float* WcDT = wsf+1920;
  const float* bcE  = wsf+2304;   const float* bcD  = wsf+2496;
  const float* brzE = wsf+2688;   const float* brzD = wsf+2816;
  const float* EG   = wsf+2944;   const float* ebg0 = wsf+3584;
  const float* egs  = wsf+3648;   const float* egd  = wsf+3658;
  const float* c6   = wsf+3668;
  const int gt = blockIdx.x*256 + threadIdx.x;
  const int gs = gridDim.x*256;

  for (int i = gt; i < 18432; i += gs){           // B1E
    int nt=i/1536, r=i%1536, kt=r>>9, r2=r&511, lane=r2>>3, j=r2&7;
    int k=kt*32+(lane>>4)*8+j, n=nt*16+(lane&15);
    float v=0.f;
    if (k < 64) v = enc_Whh[n*64+k];
    else if (k < 74){ if (n < 128) v = WcET[n*10+(k-64)]; }
    else if (k == 74) v = (n < 128) ? brzE[n] : enc_bhh[n];
    wsb[i]=f2b(v);
  }
  for (int i = gt; i < 2048; i += gs){            // B2E
    int nt=i>>9, r2=i&511, lane=r2>>3, j=r2&7;
    int k=64+(lane>>4)*8+j, n=128+nt*16+(lane&15);
    float v=0.f;
    if (k < 74) v = WcET[n*10+(k-64)];
    else if (k == 74) v = bcE[n];
    wsb[18432+i]=f2b(v);
  }
  for (int i = gt; i < 18432; i += gs){           // B1D
    int nt=i/1536, r=i%1536, kt=r>>9, r2=r&511, lane=r2>>3, j=r2&7;
    int k=kt*32+(lane>>4)*8+j, n=nt*16+(lane&15);
    float v=0.f;
    if (k < 64) v = dec_Whh[n*64+k];
    else if (k < 66){ if (n < 128) v = WcDT[n*2+(k-64)]; }
    else if (k == 66) v = (n < 128) ? brzD[n] : dec_bhh[n];
    wsb[20480+i]=f2b(v);
  }
  for (int i = gt; i < 2048; i += gs){            // B2D
    int nt=i>>9, r2=i&511, lane=r2>>3, j=r2&7;
    int k=64+(lane>>4)*8+j, n=128+nt*16+(lane&15);
    float v=0.f;
    if (k < 66) v = WcDT[n*2+(k-64)];
    else if (k == 66) v = bcD[n];
    wsb[38912+i]=f2b(v);
  }
  for (int i = gt; i < 2560; i += gs){            // B3
    int nt=i>>9, r2=i&511, lane=r2>>3, j=r2&7;
    int k=64+(lane>>4)*8+j, n=nt*16+(lane&15);
    float v=0.f;
    if (k < 74){ int f=k-64;
      if (n < 64) v = EG[f*64+n]; else if (n == 64) v = egs[f]; else if (n == 65) v = egd[f];
    } else if (k == 74){
      if (n < 64) v = ebg0[n]+gat_b[n]; else if (n == 64) v = c6[0]; else if (n == 65) v = c6[1];
    }
    wsb[40960+i]=f2b(v);
  }
  for (int i = gt; i < 4096; i += gs){            // BW1 / BC1
    int nt=i>>10, r=i&1023, kt=r>>9, r2=r&511, lane=r2>>3, j=r2&7;
    int k=kt*32+(lane>>4)*8+j, n=nt*16+(lane&15);
    wsb[43520+i]=f2b(out_W1 [k*64+n]);
    wsb[48640+i]=f2b(conf_W1[k*64+n]);
  }
  for (int i = gt; i < 1024; i += gs){            // BW2 / BC2
    int kt=i>>9, r2=i&511, lane=r2>>3, j=r2&7;
    int k=kt*32+(lane>>4)*8+j, n=lane&15;
    wsb[47616+i]=f2b(n<10 ? out_W2 [k*10+n] : 0.f);
    wsb[52736+i]=f2b(n<5  ? conf_W2[k*5 +n] : 0.f);
  }
}

// One GRU step on a wave's private 16-row tile. ALL GRU B fragments from LDS
// (round-6 lesson: per-step global B reads thrash L2 -> 585MB HBM fetch).
// Wave-private LDS traffic -> no cross-wave barrier; wave_barrier pins order.
__device__ __forceinline__ void gru_mfma_step(const short* Bs,
    short* hS, float (&hcd)[4][4], bf16x8 af2, int wid, int lane)
{
  const int g = lane>>4, l15 = lane&15;
  const int arow = wid*16 + l15;
  const int sw = arow & 7;
  bf16x8 af0 = *(const bf16x8*)&hS[arow*64 + (((0+g) ^ sw)<<3)];
  bf16x8 af1 = *(const bf16x8*)&hS[arow*64 + (((4+g) ^ sw)<<3)];
  f32x4 acc[12];
  #pragma unroll
  for (int nt = 0; nt < 12; nt++){
    f32x4 a = {0.f,0.f,0.f,0.f};
    a = MFMA16(af0, *(const bf16x8*)&Bs[(nt*3+0)*512 + lane*8], a);
    a = MFMA16(af1, *(const bf16x8*)&Bs[(nt*3+1)*512 + lane*8], a);
    a = MFMA16(af2, *(const bf16x8*)&Bs[(nt*3+2)*512 + lane*8], a);
    acc[nt] = a;
  }
  f32x4 accx[4];
  #pragma unroll
  for (int nt = 0; nt < 4; nt++){
    f32x4 a = {0.f,0.f,0.f,0.f};
    accx[nt] = MFMA16(af2, *(const bf16x8*)&Bs[18432 + nt*512 + lane*8], a);
  }
  #pragma unroll
  for (int nt = 0; nt < 4; nt++){
    #pragma unroll
    for (int j = 0; j < 4; j++){
      float r  = sigm(acc[nt][j]);
      float z  = sigm(acc[nt+4][j]);
      float ng = tanh_f(accx[nt][j] + r*acc[nt+8][j]);
      float hn = (1.f - z)*ng + z*hcd[nt][j];
      hcd[nt][j] = hn;
      hS[hswz(wid*16 + 4*g + j, nt*16 + l15)] = f2b(hn);
    }
  }
  __builtin_amdgcn_wave_barrier();
}

__global__ __launch_bounds__(512, 2) void model_kernel(
    const float* __restrict__ x, const short* __restrict__ wsb,
    const float* __restrict__ out_b1, const float* __restrict__ out_b2,
    const float* __restrict__ conf_b1, const float* __restrict__ conf_b2,
    float* __restrict__ traj, float* __restrict__ conf, int B)
{
  __shared__ __align__(16) short Bs[20480];       // full GRU B1+B2 (enc->dec)
  __shared__ __align__(16) short hS[ROWS*64];     // h tile, bf16 swizzled
  __shared__ __align__(16) short sS[ROWS*64];     // xl / relu-s overlay
  __shared__ float xyS[ROWS*2];
  __shared__ float asdS[ROWS*2];
  __shared__ float maskS[ROWS];

  const int tid = threadIdx.x;
  const int wid = tid>>6, lane = tid&63;
  const int g = lane>>4, l15 = lane&15;
  const int BN = B*NNODE;
  const int br0 = blockIdx.x*ACTR;
  const int arow = wid*16 + l15;
  const short ONE = 0x3F80;

  float b1r[4], cb1r[4];
  #pragma unroll
  for (int nt = 0; nt < 4; nt++){ b1r[nt]=out_b1[nt*16+l15]; cb1r[nt]=conf_b1[nt*16+l15]; }
  const float b2r  = out_b2 [l15<10 ? l15 : 0];
  const float cb2r = conf_b2[l15<5  ? l15 : 0];

  int growA = br0 + arow; if (growA > BN-1) growA = BN-1;
  const float* xrow = x + (size_t)(growA/5)*250 + (growA%5)*10;

  for (int i = tid; i < 2560; i += 512) ((int4*)Bs)[i] = ((const int4*)wsb)[i];
  for (int i = tid; i < ROWS*64; i += 512) hS[i] = 0;
  float hcd[4][4];
  #pragma unroll
  for (int a1=0;a1<4;a1++){
    #pragma unroll
    for (int a2=0;a2<4;a2++) hcd[a1][a2]=0.f;
  }
  __syncthreads();

  // ---------------- GRU encoder (wave-private; no barriers) ----------------
  for (int t = 0; t < TIN; t++){
    bf16x8 af2 = {0,0,0,0,0,0,0,0};
    if (g == 0){
      const float2* p = (const float2*)(xrow + t*50);
      float2 v0=p[0], v1=p[1], v2=p[2], v3=p[3];
      af2[0]=f2b(v0.x); af2[1]=f2b(v0.y); af2[2]=f2b(v1.x); af2[3]=f2b(v1.y);
      af2[4]=f2b(v2.x); af2[5]=f2b(v2.y); af2[6]=f2b(v3.x); af2[7]=f2b(v3.y);
    } else if (g == 1){
      const float2* p = (const float2*)(xrow + t*50 + 8);
      float2 v4=p[0];
      af2[0]=f2b(v4.x); af2[1]=f2b(v4.y); af2[2]=ONE;
    }
    gru_mfma_step(Bs, hS, hcd, af2, wid, lane);
  }

  // ---------------- GAT ----------------
  {
    bf16x8 af2 = {0,0,0,0,0,0,0,0};
    if (g == 0){
      const float2* p = (const float2*)(xrow + 4*50);
      float2 v0=p[0], v1=p[1], v2=p[2], v3=p[3];
      af2[0]=f2b(v0.x); af2[1]=f2b(v0.y); af2[2]=f2b(v1.x); af2[3]=f2b(v1.y);
      af2[4]=f2b(v2.x); af2[5]=f2b(v2.y); af2[6]=f2b(v3.x); af2[7]=f2b(v3.y);
      float msum = v0.x+v0.y+v1.x+v1.y+v2.x+v2.y;
      maskS[arow] = (msum != 0.f) ? 1.f : 0.f;
      xyS[arow*2]   = v0.x;
      xyS[arow*2+1] = v0.y;
    } else if (g == 1){
      const float2* p = (const float2*)(xrow + 4*50 + 8);
      float2 v4=p[0];
      af2[0]=f2b(v4.x); af2[1]=f2b(v4.y); af2[2]=ONE;
    }
    #pragma unroll
    for (int nt = 0; nt < 5; nt++){
      f32x4 a = {0.f,0.f,0.f,0.f};
      a = MFMA16(af2, *(const bf16x8*)(wsb + 40960 + nt*512 + lane*8), a);
      if (nt < 4){
        #pragma unroll
        for (int j = 0; j < 4; j++)
          sS[(wid*16 + 4*g + j)*64 + nt*16 + l15] = f2b(a[j]);   // xl plain layout
      } else if (l15 < 2){
        #pragma unroll
        for (int j = 0; j < 4; j++)
          asdS[(wid*16 + 4*g + j)*2 + l15] = a[j];               // a_s / a_d
      }
    }
  }
  __syncthreads();                                   // cross-wave: aggregation
  {   // aggregation: 4 threads per dst row, 16 cols each
    int dst = tid >> 2, cb = tid & 3;
    if (dst < ACTR){
      int nd = dst % 5, bas = dst - nd;
      float ad  = asdS[dst*2+1];
      float mkD = maskS[dst];
      float al[5], mx = -1e30f;
      #pragma unroll
      for (int i = 0; i < 5; i++){
        float a = asdS[(bas+i)*2] + ad;
        a = (a > 0.f) ? a : 0.2f*a;
        bool valid = (i == nd) || (maskS[bas+i] != 0.f && mkD != 0.f);
        al[i] = valid ? a : -1e30f;
        mx = fmaxf(mx, al[i]);
      }
      float w5[5], es = 0.f;
      #pragma unroll
      for (int i = 0; i < 5; i++){ float e = (al[i] > -1e29f) ? __expf(al[i]-mx) : 0.f; w5[i]=e; es+=e; }
      float rs = fastrcp(es);
      #pragma unroll
      for (int i = 0; i < 5; i++) w5[i] *= rs;
      for (int cc = 0; cc < 16; cc++){
        int c = cb*16 + cc;
        float agg = 0.f;
        #pragma unroll
        for (int i = 0; i < 5; i++) agg += w5[i]*b2f(sS[(bas+i)*64 + c]);
        int hi = hswz(dst, c);
        hS[hi] = f2b(b2f(hS[hi]) + agg);       // h_final = h_enc + gat_out
      }
    }
  }
  __syncthreads();                                   // aggregation done
  #pragma unroll
  for (int nt = 0; nt < 4; nt++){
    #pragma unroll
    for (int j = 0; j < 4; j++)
      hcd[nt][j] = b2f(hS[hswz(wid*16+4*g+j, nt*16+l15)]);
  }

  // ---------------- confidence head (wave-private) ----------------
  {
    const int sw = arow & 7;
    bf16x8 hf0 = *(const bf16x8*)&hS[arow*64 + (((0+g) ^ sw)<<3)];
    bf16x8 hf1 = *(const bf16x8*)&hS[arow*64 + (((4+g) ^ sw)<<3)];
    #pragma unroll
    for (int nt = 0; nt < 4; nt++){
      f32x4 a = {0.f,0.f,0.f,0.f};
      a = MFMA16(hf0, *(const bf16x8*)(wsb + 48640 + (nt*2+0)*512 + lane*8), a);
      a = MFMA16(hf1, *(const bf16x8*)(wsb + 48640 + (nt*2+1)*512 + lane*8), a);
      #pragma unroll
      for (int j = 0; j < 4; j++)
        sS[hswz(wid*16+4*g+j, nt*16+l15)] = f2b(fmaxf(a[j] + cb1r[nt], 0.f));
    }
    __builtin_amdgcn_wave_barrier();
    bf16x8 sf0 = *(const bf16x8*)&sS[arow*64 + (((0+g) ^ sw)<<3)];
    bf16x8 sf1 = *(const bf16x8*)&sS[arow*64 + (((4+g) ^ sw)<<3)];
    f32x4 a = {0.f,0.f,0.f,0.f};
    a = MFMA16(sf0, *(const bf16x8*)(wsb + 52736 + 0*512 + lane*8), a);
    a = MFMA16(sf1, *(const bf16x8*)(wsb + 52736 + 1*512 + lane*8), a);
    #pragma unroll
    for (int j = 0; j < 4; j++){
      float my = a[j] + cb2r;
      float v0 = __shfl(my, (lane&48)+0, 64);
      float v1 = __shfl(my, (lane&48)+1, 64);
      float v2 = __shfl(my, (lane&48)+2, 64);
      float v3 = __shfl(my, (lane&48)+3, 64);
      float v4 = __shfl(my, (lane&48)+4, 64);
      float mx = fmaxf(fmaxf(fmaxf(v0,v1),fmaxf(v2,v3)),v4);
      float es = __expf(v0-mx)+__expf(v1-mx)+__expf(v2-mx)+__expf(v3-mx)+__expf(v4-mx);
      int lrow = wid*16 + 4*g + j;
      int gr = br0 + lrow;
      if (l15 < 5 && lrow < ACTR && gr < BN){
        int samp = gr/5, node = gr - samp*5;
        conf[((size_t)samp*NMODE + l15)*NNODE + node] = __expf(my-mx)*fastrcp(es);
      }
    }
  }

  // ---------------- reload decoder B ----------------
  __syncthreads();                                   // all waves done with enc Bs
  for (int i = tid; i < 2560; i += 512) ((int4*)Bs)[i] = ((const int4*)(wsb + 20480))[i];
  __syncthreads();                                   // dec Bs ready

  // ---------------- GRUCell decoder (wave-private) ----------------
  for (int t = 0; t < TOUT; t++){
    bf16x8 af2 = {0,0,0,0,0,0,0,0};
    if (g == 0){
      af2[0] = f2b(xyS[arow*2]);
      af2[1] = f2b(xyS[arow*2+1]);
      af2[2] = ONE;
    }
    gru_mfma_step(Bs, hS, hcd, af2, wid, lane);

    const int sw = arow & 7;
    bf16x8 hf0 = *(const bf16x8*)&hS[arow*64 + (((0+g) ^ sw)<<3)];
    bf16x8 hf1 = *(const bf16x8*)&hS[arow*64 + (((4+g) ^ sw)<<3)];
    #pragma unroll
    for (int nt = 0; nt < 4; nt++){
      f32x4 a = {0.f,0.f,0.f,0.f};
      a = MFMA16(hf0, *(const bf16x8*)(wsb + 43520 + (nt*2+0)*512 + lane*8), a);
      a = MFMA16(hf1, *(const bf16x8*)(wsb + 43520 + (nt*2+1)*512 + lane*8), a);
      #pragma unroll
      for (int j = 0; j < 4; j++)
        sS[hswz(wid*16+4*g+j, nt*16+l15)] = f2b(fmaxf(a[j] + b1r[nt], 0.f));
    }
    __builtin_amdgcn_wave_barrier();
    bf16x8 sf0 = *(const bf16x8*)&sS[arow*64 + (((0+g) ^ sw)<<3)];
    bf16x8 sf1 = *(const bf16x8*)&sS[arow*64 + (((4+g) ^ sw)<<3)];
    f32x4 oo = {0.f,0.f,0.f,0.f};
    oo = MFMA16(sf0, *(const bf16x8*)(wsb + 47616 + 0*512 + lane*8), oo);
    oo = MFMA16(sf1, *(const bf16x8*)(wsb + 47616 + 1*512 + lane*8), oo);
    #pragma unroll
    for (int j = 0; j < 4; j++){
      float ov = oo[j] + b2r;
      int lrow = wid*16 + 4*g + j;
      int gr = br0 + lrow;
      if (l15 < 10 && lrow < ACTR && gr < BN){
        int samp = gr/5, node = gr - samp*5;
        int cc = (l15 >= 5) ? 1 : 0;
        int m = l15 - 5*cc;
        traj[((size_t)(samp*NMODE + m)*NNODE + node)*(TOUT*2) + t*2 + cc] = ov;
      }
      if (l15 == 0) xyS[lrow*2]   = ov;    // mode-0 x fed back (own wave rows)
      if (l15 == 5) xyS[lrow*2+1] = ov;
    }
    __builtin_amdgcn_wave_barrier();
  }
}

extern "C" void kernel_launch(void* const* d_in, const int* in_sizes, int n_in,
                              void* d_out, int out_size, void* d_ws, size_t ws_size,
                              hipStream_t stream)
{
  const float* x           = (const float*)d_in[0];
  const float* embed_W     = (const float*)d_in[1];
  const float* embed_b     = (const float*)d_in[2];
  const float* gat_W       = (const float*)d_in[3];
  const float* gat_att_src = (const float*)d_in[4];
  const float* gat_att_dst = (const float*)d_in[5];
  const float* gat_b       = (const float*)d_in[6];
  const float* enc_Wih     = (const float*)d_in[7];
  const float* enc_Whh     = (const float*)d_in[8];
  const float* enc_bih     = (const float*)d_in[9];
  const float* enc_bhh     = (const float*)d_in[10];
  const float* dec_Wih     = (const float*)d_in[11];
  const float* dec_Whh     = (const float*)d_in[12];
  const float* dec_bih     = (const float*)d_in[13];
  const float* dec_bhh     = (const float*)d_in[14];
  const float* out_W1      = (const float*)d_in[15];
  const float* out_b1      = (const float*)d_in[16];
  const float* out_W2      = (const float*)d_in[17];
  const float* out_b2      = (const float*)d_in[18];
  const float* proj_W      = (const float*)d_in[19];
  const float* proj_b      = (const float*)d_in[20];
  const float* conf_W1     = (const float*)d_in[21];
  const float* conf_b1     = (const float*)d_in[22];
  const float* conf_W2     = (const float*)d_in[23];
  const float* conf_b2     = (const float*)d_in[24];

  const int B = in_sizes[0] / (TIN*NNODE*FD);
  const int BN = B*NNODE;
  short* wsb = (short*)d_ws;
  float* traj = (float*)d_out;
  float* conf = traj + (size_t)B*NMODE*NNODE*TOUT*2;

  setup_fold<<<4, 256, 0, stream>>>(embed_W, embed_b, enc_Wih, enc_bih,
                                    dec_Wih, dec_bih, proj_W, proj_b,
                                    gat_W, gat_att_src, gat_att_dst,
                                    enc_bhh, dec_bhh, wsb);
  setup_frag<<<64, 256, 0, stream>>>(enc_Whh, enc_bhh, dec_Whh, dec_bhh, gat_b,
                                     out_W1, out_W2, conf_W1, conf_W2, wsb);

  const int blocks = (BN + ACTR - 1)/ACTR;
  model_kernel<<<blocks, 512, 0, stream>>>(x, wsb, out_b1, out_b2, conf_b1, conf_b2,
                                           traj, conf, B);
}